// Round 2
// baseline (342.480 us; speedup 1.0000x reference)
//
#include <hip/hip_runtime.h>
#include <math.h>

#define N_NODES 100000
#define N_EDGES 1600000

#define NT_BLOCKS ((N_NODES + 63) / 64)       // 1563 nodeT blocks (64 nodes each)
#define E4 (N_EDGES / 4)                      // 400000 int4 edge packets
#define E_BLOCKS ((E4 + 255) / 256)           // 1563 edge blocks (1 int4/thread)

typedef int i32x4 __attribute__((ext_vector_type(4)));

// ---------------------------------------------------------------------------
// K1: nodeT = feat @ Q + c where Q = W_in @ P (64x4), c = b_in @ P,
// P = [W_u, W_out[:,0], W_out[:,1], W_v]  (hidden layer algebraically
// collapsed: nodeT[n] = (h_n.W_u, h_n.Wout0, h_n.Wout1, h_n.W_v)).
// Also zeroes agg (saves a memset dispatch; K2 is stream-ordered after us).
// ---------------------------------------------------------------------------
__global__ __launch_bounds__(256) void node_kernel(
    const float* __restrict__ feat,
    const float* __restrict__ W_in,
    const float* __restrict__ b_in,
    const float* __restrict__ W_edge,
    const float* __restrict__ W_out,
    float4* __restrict__ nodeT,
    float4* __restrict__ agg)
{
    const int tid = threadIdx.x;

    __shared__ float sP[64 * 4];   // P[m][j] row-major
    __shared__ float sQ[64 * 4];   // Q[k][j] row-major, 16B rows
    __shared__ float sc[4];

    if (tid < 64) {
        sP[tid * 4 + 0] = W_edge[tid];            // W_u
        sP[tid * 4 + 1] = W_out[tid * 2 + 0];     // W_out[:,0]
        sP[tid * 4 + 2] = W_out[tid * 2 + 1];     // W_out[:,1]
        sP[tid * 4 + 3] = W_edge[64 + tid];       // W_v
    }
    // zero agg for K2's atomics (64 nodes per block)
    if (tid < 64) {
        const int n = blockIdx.x * 64 + tid;
        if (n < N_NODES) agg[n] = make_float4(0.f, 0.f, 0.f, 0.f);
    }
    __syncthreads();

    {   // Q[k][j] = sum_m W_in[k][m] * P[m][j]
        const int k = tid >> 2, j = tid & 3;
        float q = 0.f;
        for (int m = 0; m < 64; ++m) q += W_in[k * 64 + m] * sP[m * 4 + j];
        sQ[k * 4 + j] = q;
        if (tid < 4) {
            float cc = 0.f;
            for (int m = 0; m < 64; ++m) cc += b_in[m] * sP[m * 4 + tid];
            sc[tid] = cc;
        }
    }
    __syncthreads();

    const int lane = tid & 63;
    const int wv   = tid >> 6;
    const int n    = blockIdx.x * 64 + wv * 16 + (lane >> 2);  // 16 nodes/wave
    const int ks   = (lane & 3) << 4;                          // 16 k's/lane

    float p0 = 0.f, p1 = 0.f, p2 = 0.f, p3 = 0.f;
    if (n < N_NODES) {
        const float* fr = feat + (size_t)n * 64 + ks;
        #pragma unroll
        for (int i4 = 0; i4 < 4; ++i4) {
            const float4 f = *(const float4*)(fr + i4 * 4);
            const float fv[4] = {f.x, f.y, f.z, f.w};
            #pragma unroll
            for (int u = 0; u < 4; ++u) {
                const float4 q = *(const float4*)&sQ[(ks + i4 * 4 + u) * 4];
                p0 += fv[u] * q.x;
                p1 += fv[u] * q.y;
                p2 += fv[u] * q.z;
                p3 += fv[u] * q.w;
            }
        }
    }
    #pragma unroll
    for (int off = 1; off <= 2; off <<= 1) {
        p0 += __shfl_xor(p0, off);
        p1 += __shfl_xor(p1, off);
        p2 += __shfl_xor(p2, off);
        p3 += __shfl_xor(p3, off);
    }
    if (n < N_NODES && (lane & 3) == 0)
        nodeT[n] = make_float4(p0 + sc[0], p1 + sc[1], p2 + sc[2], p3 + sc[3]);
}

// ---------------------------------------------------------------------------
// K2: edge-parallel scatter-aggregate. One int4 of src + dst per thread
// (coalesced, nontemporal so the 12.8 MB edge stream doesn't evict the
// 1.6 MB L2-resident nodeT). Per edge: gather nodeT[src] (16B L2 hit) +
// nodeT[dst].w (4B), sigmoid, 3x hardware fp32 atomic add into agg[dst]
// (m0, m1, count). unsafeAtomicAdd -> global_atomic_add_f32 (native on
// gfx950, device-scope, performed at the coherent point - cross-XCD safe).
// ~16 edges/node mean, spread over 131k lines: low contention.
// ---------------------------------------------------------------------------
__global__ __launch_bounds__(256) void edge_kernel(
    const int* __restrict__ src,
    const int* __restrict__ dst,
    const float4* __restrict__ nodeT,
    const float* __restrict__ b_edge,
    float4* __restrict__ agg)
{
    const int idx = blockIdx.x * 256 + threadIdx.x;
    if (idx >= E4) return;

    const float be = b_edge[0];
    const i32x4 sv = __builtin_nontemporal_load(((const i32x4*)src) + idx);
    const i32x4 dv = __builtin_nontemporal_load(((const i32x4*)dst) + idx);
    const float* nT = (const float*)nodeT;

    #pragma unroll
    for (int u = 0; u < 4; ++u) {
        const int s = sv[u];
        const int d = dv[u];
        const float4 ts  = nodeT[s];
        const float  tdw = nT[4 * d + 3];
        const float  w   = 1.0f / (1.0f + __expf(-(ts.x + tdw + be)));
        float* a = (float*)&agg[d];
        unsafeAtomicAdd(a + 0, w * ts.y);
        unsafeAtomicAdd(a + 1, w * ts.z);
        unsafeAtomicAdd(a + 2, 1.0f);
    }
}

// ---------------------------------------------------------------------------
// K3: finalize. out[n] = (deg>0 ? agg : nodeT fallback) + b_out.
// ---------------------------------------------------------------------------
__global__ __launch_bounds__(256) void final_kernel(
    const float4* __restrict__ nodeT,
    const float4* __restrict__ agg,
    const float* __restrict__ b_out,
    float2* __restrict__ out)
{
    const int n = blockIdx.x * 256 + threadIdx.x;
    if (n >= N_NODES) return;
    const float4 a = agg[n];
    const float4 t = nodeT[n];
    const float bo0 = b_out[0];
    const float bo1 = b_out[1];
    const bool  has = a.z > 0.f;
    out[n] = make_float2((has ? a.x : t.y) + bo0,
                         (has ? a.y : t.z) + bo1);
}

// ---------------------------------------------------------------------------
extern "C" void kernel_launch(void* const* d_in, const int* in_sizes, int n_in,
                              void* d_out, int out_size, void* d_ws, size_t ws_size,
                              hipStream_t stream) {
    const float* feat   = (const float*)d_in[0];
    const int*   src    = (const int*)d_in[1];
    const int*   dst    = (const int*)d_in[2];
    const float* W_in   = (const float*)d_in[3];
    const float* b_in   = (const float*)d_in[4];
    const float* W_edge = (const float*)d_in[5];
    const float* b_edge = (const float*)d_in[6];
    const float* W_out  = (const float*)d_in[7];
    const float* b_out  = (const float*)d_in[8];
    float2* out = (float2*)d_out;

    // workspace: nodeT (1.6 MB) | agg (1.6 MB)
    float4* nodeT = (float4*)d_ws;
    float4* agg   = nodeT + N_NODES;

    node_kernel<<<NT_BLOCKS, 256, 0, stream>>>(
        feat, W_in, b_in, W_edge, W_out, nodeT, agg);
    edge_kernel<<<E_BLOCKS, 256, 0, stream>>>(
        src, dst, nodeT, b_edge, agg);
    final_kernel<<<(N_NODES + 255) / 256, 256, 0, stream>>>(
        nodeT, agg, b_out, out);
}

// Round 3
// 137.589 us; speedup vs baseline: 2.4891x; 2.4891x over previous
//
#include <hip/hip_runtime.h>
#include <math.h>

#define N_NODES 100000
#define N_EDGES 1600000

#define BK_LOG 7
#define BKW 128                               // nodes per bucket
#define NBK ((N_NODES + BKW - 1) / BKW)       // 782 buckets
#define CAPB 2688   // per-bucket capacity; mean 2048, sigma~45 -> +14 sigma
#define UNS4 3      // int4 load rounds in agg (3*256*4 = 3072 >= CAPB)

#define GS 128                                // scatter blocks (grid-first)
#define EPS (N_EDGES / GS)                    // 12500 edges per block (exact)
#define EPS4 (EPS / 4)                        // 3125 int4 per block
#define SROUNDS ((EPS4 + 255) / 256)          // 13 load rounds

#define NT_BLOCKS ((N_NODES + 63) / 64)       // 1563 nodeT blocks (64 nodes each)

// ---------------------------------------------------------------------------
// K1 (mixed grid): blocks [0, GS) scatter edges into fixed-capacity 128-node
// bucket regions. Two-pass (histogram -> ONE global cursor atomic per
// non-empty (block,bucket) -> re-read (L2-hot) + rank + write). GS=128 gives
// avg 16 records per (block,bucket) run = one full 64B line per writer block
// (no cross-XCD partial-line ping-pong), and only ~100K cursor atomics.
// Blocks [GS, GS+NT_BLOCKS) compute nodeT = feat @ Q + c where Q = W_in @ P,
// c = b_in @ P, P = [W_u, W_out[:,0], W_out[:,1], W_v] (hidden layer
// algebraically collapsed). Record: ((dst&127)<<17 | src), src < 2^17.
// ---------------------------------------------------------------------------
__global__ __launch_bounds__(256) void prep_kernel(
    const float* __restrict__ feat,
    const float* __restrict__ W_in,
    const float* __restrict__ b_in,
    const float* __restrict__ W_edge,
    const float* __restrict__ W_out,
    const int*   __restrict__ src,
    const int*   __restrict__ dst,
    int* __restrict__ cursor,
    int* __restrict__ ework,
    float4* __restrict__ nodeT)
{
    const int tid = threadIdx.x;

    // ---------------- scatter blocks ----------------
    if ((int)blockIdx.x < GS) {
        __shared__ int hist[NBK];    // pass-1 counts
        __shared__ int rhist[NBK];   // pass-2 ranks
        __shared__ int gbase[NBK];   // global base from cursor
        for (int i = tid; i < NBK; i += 256) { hist[i] = 0; rhist[i] = 0; }
        __syncthreads();

        const int4* src4 = (const int4*)src;
        const int4* dst4 = (const int4*)dst;
        const int   b40  = (int)blockIdx.x * EPS4;

        // pass 1: histogram dst buckets
        for (int j = 0; j < SROUNDS; ++j) {
            const int o4 = j * 256 + tid;
            if (o4 < EPS4) {
                const int4 d4 = dst4[b40 + o4];
                atomicAdd(&hist[d4.x >> BK_LOG], 1);
                atomicAdd(&hist[d4.y >> BK_LOG], 1);
                atomicAdd(&hist[d4.z >> BK_LOG], 1);
                atomicAdd(&hist[d4.w >> BK_LOG], 1);
            }
        }
        __syncthreads();

        // one global cursor atomic per non-empty bucket
        for (int i = tid; i < NBK; i += 256) {
            const int c = hist[i];
            if (c) gbase[i] = atomicAdd(&cursor[i], c);
        }
        __syncthreads();

        // pass 2: re-read (L2-hot), rank, write packed records
        for (int j = 0; j < SROUNDS; ++j) {
            const int o4 = j * 256 + tid;
            if (o4 < EPS4) {
                const int4 d4 = dst4[b40 + o4];
                const int4 s4 = src4[b40 + o4];
                const int dv[4] = {d4.x, d4.y, d4.z, d4.w};
                const int sv[4] = {s4.x, s4.y, s4.z, s4.w};
                #pragma unroll
                for (int u = 0; u < 4; ++u) {
                    const int d = dv[u];
                    const int b = d >> BK_LOG;
                    const int r = atomicAdd(&rhist[b], 1);
                    ework[b * CAPB + gbase[b] + r] =
                        ((d & (BKW - 1)) << 17) | sv[u];
                }
            }
        }
        return;
    }

    // ---------------- nodeT blocks ----------------
    __shared__ float sP[64 * 4];   // P[m][j] row-major
    __shared__ float sQ[64 * 4];   // Q[k][j] row-major, 16B rows
    __shared__ float sc[4];

    if (tid < 64) {
        sP[tid * 4 + 0] = W_edge[tid];            // W_u
        sP[tid * 4 + 1] = W_out[tid * 2 + 0];     // W_out[:,0]
        sP[tid * 4 + 2] = W_out[tid * 2 + 1];     // W_out[:,1]
        sP[tid * 4 + 3] = W_edge[64 + tid];       // W_v
    }
    __syncthreads();

    {   // Q[k][j] = sum_m W_in[k][m] * P[m][j]
        const int k = tid >> 2, j = tid & 3;
        float q = 0.f;
        for (int m = 0; m < 64; ++m) q += W_in[k * 64 + m] * sP[m * 4 + j];
        sQ[k * 4 + j] = q;
        if (tid < 4) {
            float cc = 0.f;
            for (int m = 0; m < 64; ++m) cc += b_in[m] * sP[m * 4 + tid];
            sc[tid] = cc;
        }
    }
    __syncthreads();

    const int lane = tid & 63;
    const int wv   = tid >> 6;
    const int n    = ((int)blockIdx.x - GS) * 64 + wv * 16 + (lane >> 2);
    const int ks   = (lane & 3) << 4;                           // 16 k's/lane

    float p0 = 0.f, p1 = 0.f, p2 = 0.f, p3 = 0.f;
    if (n < N_NODES) {
        const float* fr = feat + (size_t)n * 64 + ks;
        #pragma unroll
        for (int i4 = 0; i4 < 4; ++i4) {
            const float4 f = *(const float4*)(fr + i4 * 4);
            const float fv[4] = {f.x, f.y, f.z, f.w};
            #pragma unroll
            for (int u = 0; u < 4; ++u) {
                const float4 q = *(const float4*)&sQ[(ks + i4 * 4 + u) * 4];
                p0 += fv[u] * q.x;
                p1 += fv[u] * q.y;
                p2 += fv[u] * q.z;
                p3 += fv[u] * q.w;
            }
        }
    }
    #pragma unroll
    for (int off = 1; off <= 2; off <<= 1) {
        p0 += __shfl_xor(p0, off);
        p1 += __shfl_xor(p1, off);
        p2 += __shfl_xor(p2, off);
        p3 += __shfl_xor(p3, off);
    }
    if (n < N_NODES && (lane & 3) == 0)
        nodeT[n] = make_float4(p0 + sc[0], p1 + sc[1], p2 + sc[2], p3 + sc[3]);
}

// ---------------------------------------------------------------------------
// K2: unsorted aggregation via LDS fp32 atomics (ds_add_f32 -- per-CU LDS
// unit, NOT the slow cross-XCD global atomic path). One block per 128-node
// bucket, 782 blocks, 3.5 KB LDS. Per record: gather nodeT[src] (16B,
// L2-resident), sigmoid, 3 LDS atomic adds (m0, m1, count). No rank, no
// scan, no place, no ordered gather -- aggregation is commutative.
// Finalize fused: out written straight from the LDS accumulators.
// ---------------------------------------------------------------------------
__global__ __launch_bounds__(256) void agg_kernel(
    const int* __restrict__ ework,
    const int* __restrict__ cursor,
    const float4* __restrict__ nodeT,
    const float* __restrict__ b_edge,
    const float* __restrict__ b_out,
    float2* __restrict__ out)
{
    __shared__ float4 sT[BKW];   // .w pre-biased with b_edge; .y/.z fallback
    __shared__ float  aM0[BKW];
    __shared__ float  aM1[BKW];
    __shared__ int    aC[BKW];

    const int b   = blockIdx.x;
    const int tid = threadIdx.x;

    if (tid < BKW) {
        const int n = b * BKW + tid;
        float4 t = make_float4(0.f, 0.f, 0.f, 0.f);
        if (n < N_NODES) t = nodeT[n];
        t.w += b_edge[0];
        sT[tid] = t;
        aM0[tid] = 0.f;
        aM1[tid] = 0.f;
        aC[tid]  = 0;
    }
    __syncthreads();

    const int cnt = min(cursor[b], CAPB);
    const int4* ew4 = (const int4*)(ework + b * CAPB);   // CAPB*4 % 16 == 0

    #pragma unroll
    for (int j = 0; j < UNS4; ++j) {
        const int o = (j * 256 + tid) * 4;
        if (o < cnt) {
            const int4 v = ew4[j * 256 + tid];
            const int ve[4] = {v.x, v.y, v.z, v.w};
            #pragma unroll
            for (int u = 0; u < 4; ++u) {
                if (o + u < cnt) {
                    const int    l = ve[u] >> 17;
                    const int    s = ve[u] & 0x1FFFF;
                    const float4 t = nodeT[s];
                    const float  w = 1.0f / (1.0f + __expf(-(t.x + sT[l].w)));
                    atomicAdd(&aM0[l], w * t.y);
                    atomicAdd(&aM1[l], w * t.z);
                    atomicAdd(&aC[l], 1);
                }
            }
        }
    }
    __syncthreads();

    if (tid < BKW) {
        const int n = b * BKW + tid;
        if (n < N_NODES) {
            const bool has = aC[tid] > 0;
            out[n] = make_float2((has ? aM0[tid] : sT[tid].y) + b_out[0],
                                 (has ? aM1[tid] : sT[tid].z) + b_out[1]);
        }
    }
}

// ---------------------------------------------------------------------------
extern "C" void kernel_launch(void* const* d_in, const int* in_sizes, int n_in,
                              void* d_out, int out_size, void* d_ws, size_t ws_size,
                              hipStream_t stream) {
    const float* feat   = (const float*)d_in[0];
    const int*   src    = (const int*)d_in[1];
    const int*   dst    = (const int*)d_in[2];
    const float* W_in   = (const float*)d_in[3];
    const float* b_in   = (const float*)d_in[4];
    const float* W_edge = (const float*)d_in[5];
    const float* b_edge = (const float*)d_in[6];
    const float* W_out  = (const float*)d_in[7];
    const float* b_out  = (const float*)d_in[8];
    float2* out = (float2*)d_out;

    // workspace layout (16B-aligned blocks first)
    float4* nodeT  = (float4*)d_ws;                 // 1.6 MB
    int*    ework  = (int*)(nodeT + N_NODES);       // NBK*CAPB ints (8.4 MB)
    int*    cursor = ework + NBK * CAPB;            // NBK ints

    hipMemsetAsync(cursor, 0, NBK * sizeof(int), stream);

    prep_kernel<<<GS + NT_BLOCKS, 256, 0, stream>>>(
        feat, W_in, b_in, W_edge, W_out, src, dst, cursor, ework, nodeT);
    agg_kernel<<<NBK, 256, 0, stream>>>(
        ework, cursor, nodeT, b_edge, b_out, out);
}